// Round 5
// baseline (288.143 us; speedup 1.0000x reference)
//
#include <hip/hip_runtime.h>
#include <hip/hip_bf16.h>
#include <math.h>

#define BB 2
#define SS 2048
#define DD 1024
#define HH 16
#define DKK 64
#define BH (BB * HH)          // 32

typedef __bf16 bf16_t;
typedef _Float16 f16_t;
typedef __attribute__((ext_vector_type(8))) _Float16 f16x8;
typedef __attribute__((ext_vector_type(4))) _Float16 f16x4;
typedef __attribute__((ext_vector_type(4))) float f32x4;
typedef __attribute__((ext_vector_type(4))) int i32x4;
typedef __attribute__((ext_vector_type(2))) int i32x2;

// async global->LDS, 16B per lane; lds base must be wave-uniform (lane*16 implicit)
#define GLD_LDS(gp, lp) __builtin_amdgcn_global_load_lds( \
    (const __attribute__((address_space(1))) void*)(gp),  \
    (__attribute__((address_space(3))) void*)(lp), 16, 0, 0)

static __device__ __forceinline__ int pkrtz(float a, float b) {
    auto h = __builtin_amdgcn_cvt_pkrtz(a, b);  // __fp16 ext_vector(2) on this clang
    return __builtin_bit_cast(int, h);
}

// ---------------------------------------------------------------- prep kernels
// x -> fp16, plus per-(b,128-key-block) all-keep flags
__global__ void cast_x_flags(const float* __restrict__ in, f16_t* __restrict__ out,
                             const int* __restrict__ mask, int* __restrict__ flags, int n) {
    int i = blockIdx.x * blockDim.x + threadIdx.x;
    int stride = gridDim.x * blockDim.x;
    for (; i < n; i += stride) out[i] = (f16_t)in[i];
    if (blockIdx.x == 0 && threadIdx.x < BB * (SS / 128)) {
        int f = threadIdx.x;
        int b = f / (SS / 128), t = f % (SS / 128);
        const int* p = mask + b * SS + t * 128;
        int all = 1;
        for (int j = 0; j < 128; ++j) all &= (p[j] != 0);
        flags[f] = all;
    }
}

// [Wq;Wk] -> fused fp16 hi + fp16 lo (lo = residual; may be subnormal)
__global__ void cast_wqk(const float* __restrict__ Wq, const float* __restrict__ Wk,
                         f16_t* __restrict__ hi, f16_t* __restrict__ lo, int nw) {
    int i = blockIdx.x * blockDim.x + threadIdx.x;
    int stride = gridDim.x * blockDim.x;
    for (; i < 2 * nw; i += stride) {
        float v = (i < nw) ? Wq[i] : Wk[i - nw];
        f16_t h = (f16_t)v;
        hi[i] = h;
        lo[i] = (f16_t)(v - (float)h);
    }
}

// Wv, Wo -> fp16
__global__ void cast_wvo(const float* __restrict__ Wv, const float* __restrict__ Wo,
                         f16_t* __restrict__ wv, f16_t* __restrict__ wo, int nw) {
    int i = blockIdx.x * blockDim.x + threadIdx.x;
    int stride = gridDim.x * blockDim.x;
    for (; i < 2 * nw; i += stride) {
        if (i < nw) wv[i] = (f16_t)Wv[i];
        else        wo[i - nw] = (f16_t)Wo[i - nw];
    }
}

// ---------------------------------------------------------------- fused QKV GEMM (fp16)
__global__ __launch_bounds__(256) void gemm_qkv(const f16_t* __restrict__ Af,
                                                const f16_t* __restrict__ Wqkh,
                                                const f16_t* __restrict__ Wqkl,
                                                const f16_t* __restrict__ Wvf,
                                                const float* __restrict__ bq,
                                                const float* __restrict__ bk,
                                                const float* __restrict__ bv,
                                                f16_t* __restrict__ q_o,
                                                f16_t* __restrict__ k_o,
                                                f16_t* __restrict__ vt_o,
                                                int K) {
    __shared__ __align__(16) f16_t sA[4096];
    __shared__ __align__(16) f16_t sB0[4096];
    __shared__ __align__(16) f16_t sB1[4096];

    const int tid  = threadIdx.x;
    const int wv   = tid >> 6;
    const int lane = tid & 63;
    const int quad = lane >> 4;
    const int l15  = lane & 15;
    const int wr   = wv >> 1;
    const int wc   = wv & 1;
    const int row0 = blockIdx.y * 128;
    const int col0 = blockIdx.x * 128;
    const bool isV = (col0 >= 2048);

    const f16_t* B0 = isV ? (Wvf + (long)(col0 - 2048) * K) : (Wqkh + (long)col0 * K);
    const f16_t* B1 = isV ? nullptr : (Wqkl + (long)col0 * K);

    f32x4 acc[4][4] = {};

    const int srow = tid >> 2;
    const int scol = (tid & 3) * 8;
    const long aoff = (long)(row0 + srow) * K + scol;
    const long boff = (long)srow * K + scol;

    if (isV) {
#pragma unroll 1
        for (int kb = 0; kb < K; kb += 32) {
#pragma unroll
            for (int p = 0; p < 2; ++p) {
                const long go = (long)p * 64 * K + kb;
                const int lo = p * 2048 + wv * 512;
                GLD_LDS(Af + aoff + go, sA + lo);
                GLD_LDS(B0 + boff + go, sB0 + lo);
            }
            __syncthreads();
            f16x8 af[4];
#pragma unroll
            for (int mt = 0; mt < 4; ++mt)
                af[mt] = *(const f16x8*)&sA[(wr * 64 + mt * 16 + l15) * 32 + quad * 8];
#pragma unroll
            for (int nt = 0; nt < 4; ++nt) {
                f16x8 b0 = *(const f16x8*)&sB0[(wc * 64 + nt * 16 + l15) * 32 + quad * 8];
#pragma unroll
                for (int mt = 0; mt < 4; ++mt)
                    acc[mt][nt] = __builtin_amdgcn_mfma_f32_16x16x32_f16(af[mt], b0, acc[mt][nt], 0, 0, 0);
            }
            __syncthreads();
        }
    } else {
#pragma unroll 1
        for (int kb = 0; kb < K; kb += 32) {
#pragma unroll
            for (int p = 0; p < 2; ++p) {
                const long go = (long)p * 64 * K + kb;
                const int lo = p * 2048 + wv * 512;
                GLD_LDS(Af + aoff + go, sA + lo);
                GLD_LDS(B0 + boff + go, sB0 + lo);
                GLD_LDS(B1 + boff + go, sB1 + lo);
            }
            __syncthreads();
            f16x8 af[4];
#pragma unroll
            for (int mt = 0; mt < 4; ++mt)
                af[mt] = *(const f16x8*)&sA[(wr * 64 + mt * 16 + l15) * 32 + quad * 8];
#pragma unroll
            for (int nt = 0; nt < 4; ++nt) {
                f16x8 b0 = *(const f16x8*)&sB0[(wc * 64 + nt * 16 + l15) * 32 + quad * 8];
                f16x8 b1 = *(const f16x8*)&sB1[(wc * 64 + nt * 16 + l15) * 32 + quad * 8];
#pragma unroll
                for (int mt = 0; mt < 4; ++mt) {
                    acc[mt][nt] = __builtin_amdgcn_mfma_f32_16x16x32_f16(af[mt], b0, acc[mt][nt], 0, 0, 0);
                    acc[mt][nt] = __builtin_amdgcn_mfma_f32_16x16x32_f16(af[mt], b1, acc[mt][nt], 0, 0, 0);
                }
            }
            __syncthreads();
        }
    }

    if (isV) {
#pragma unroll
        for (int nt = 0; nt < 4; ++nt) {
            const int colv = (col0 - 2048) + wc * 64 + nt * 16 + l15;  // [0,1024)
            const float bvv = bv[colv];
            const int hq = colv >> 6, dk = colv & 63;
#pragma unroll
            for (int mt = 0; mt < 4; ++mt) {
                const int grow0 = row0 + wr * 64 + mt * 16 + quad * 4;
                const int bq2 = grow0 >> 11;
                const int s0  = grow0 & (SS - 1);
                f16x4 pk;
#pragma unroll
                for (int r = 0; r < 4; ++r) pk[r] = (f16_t)(acc[mt][nt][r] + bvv);
                *(f16x4*)(vt_o + ((long)(bq2 * HH + hq) * DKK + dk) * SS + s0) = pk;
            }
        }
    } else {
        const bool isK = (col0 >= 1024);
        const float* bias = isK ? bk : bq;
        f16_t* op = isK ? k_o : q_o;
#pragma unroll
        for (int nt = 0; nt < 4; ++nt) {
            const int gcol = (col0 & 1023) + wc * 64 + nt * 16 + l15;
            const float bvv = bias[gcol];
            const int hq = gcol >> 6, dk = gcol & 63;
#pragma unroll
            for (int mt = 0; mt < 4; ++mt) {
                const int grow0 = row0 + wr * 64 + mt * 16 + quad * 4;
#pragma unroll
                for (int r = 0; r < 4; ++r) {
                    int grow = grow0 + r;
                    float vvv = acc[mt][nt][r] + bvv;
                    long off = (((long)(grow >> 11) * HH + hq) * SS + (grow & (SS - 1))) * DKK + dk;
                    op[off] = (f16_t)vvv;
                }
            }
        }
    }
}

// ---------------------------------------------------------------- O-projection GEMM (fp16 in, fp32 out)
__global__ __launch_bounds__(256) void gemm_o(const f16_t* __restrict__ Ah,
                                              const f16_t* __restrict__ Bhp,
                                              const float* __restrict__ bias,
                                              float* __restrict__ outf,
                                              int N, int K) {
    __shared__ __align__(16) f16_t lds[2048 + 4096];
    f16_t* Ash = lds;
    f16_t* Bsh = lds + 2048;

    const int tid  = threadIdx.x;
    const int wv   = tid >> 6;
    const int lane = tid & 63;
    const int quad = lane >> 4;
    const int l15  = lane & 15;
    const int wr   = wv >> 1;
    const int wc   = wv & 1;
    const int row0 = blockIdx.y * 64;
    const int col0 = blockIdx.x * 128;

    f32x4 acc[2][4] = {};

    const int srow = lane >> 2;
    const int scol = (lane & 3) * 8;
    const f16_t* gA  = Ah  + (long)(row0 + wv * 16 + srow) * K + scol;
    const f16_t* gB0 = Bhp + (long)(col0 + wv * 16 + srow) * K + scol;
    const f16_t* gB1 = Bhp + (long)(col0 + (wv + 4) * 16 + srow) * K + scol;
    f16_t* lA  = Ash + wv * 512;
    f16_t* lB0 = Bsh + wv * 512;
    f16_t* lB1 = Bsh + (wv + 4) * 512;

#pragma unroll 1
    for (int kb = 0; kb < K; kb += 32) {
        GLD_LDS(gA + kb, lA);
        GLD_LDS(gB0 + kb, lB0);
        GLD_LDS(gB1 + kb, lB1);
        __syncthreads();

        f16x8 af[2];
#pragma unroll
        for (int mt = 0; mt < 2; ++mt)
            af[mt] = *(const f16x8*)&Ash[(wr * 32 + mt * 16 + l15) * 32 + quad * 8];
#pragma unroll
        for (int nt = 0; nt < 4; ++nt) {
            f16x8 bh = *(const f16x8*)&Bsh[(wc * 64 + nt * 16 + l15) * 32 + quad * 8];
#pragma unroll
            for (int mt = 0; mt < 2; ++mt)
                acc[mt][nt] = __builtin_amdgcn_mfma_f32_16x16x32_f16(af[mt], bh, acc[mt][nt], 0, 0, 0);
        }
        __syncthreads();
    }

#pragma unroll
    for (int mt = 0; mt < 2; ++mt) {
#pragma unroll
        for (int nt = 0; nt < 4; ++nt) {
            const int gcol  = col0 + wc * 64 + nt * 16 + l15;
            const float bvv = bias[gcol];
            const int grow0 = row0 + wr * 32 + mt * 16 + quad * 4;
#pragma unroll
            for (int r = 0; r < 4; ++r)
                outf[(long)(grow0 + r) * N + gcol] = acc[mt][nt][r] + bvv;
        }
    }
}

// ---------------------------------------------------------------- MFMA flash attention v8
// v7 + (a) double-buffered K/V LDS, ONE barrier per 128-key tile, next-tile
// global_load_lds issued right after the barrier (latency hides under compute);
// (b) rowsum on the MFMA pipe: lacc = mfma_16x16x16(paf, ones, lacc) -> lacc[r]
// shares row indexing with o[t][r]: no end shuffles, no VALU adds.
__global__ __launch_bounds__(256) void attn_mfma8(const f16_t* __restrict__ Qp,
                                                  const f16_t* __restrict__ Kp,
                                                  const f16_t* __restrict__ Vtp,
                                                  const int* __restrict__ mask,
                                                  const int* __restrict__ flags,
                                                  f16_t* __restrict__ ctx,
                                                  int seq_len) {
    __shared__ __align__(16) f16_t Ksh[2][2][4096];   // [buf][64-key sub-tile][...]
    __shared__ __align__(16) f16_t Vsh[2][2][4096];   // [buf][sub-tile] of V^T [d][key]

    const int tid  = threadIdx.x;
    const int wv   = tid >> 6;
    const int lane = tid & 63;
    const int quad = lane >> 4;
    const int l15  = lane & 15;
    const int bh   = blockIdx.y;
    const int b    = bh >> 4;
    const int h    = bh & 15;
    const int q0   = blockIdx.x * 64 + wv * 16;

    const long kb = (long)bh * SS * DKK;

    f16x8 qf[2];
    {
        const f16_t* pq = Qp + kb + (long)(q0 + l15) * DKK + quad * 8;
        qf[0] = *(const f16x8*)pq;
        qf[1] = *(const f16x8*)(pq + 32);
        const f16_t qs = (f16_t)(8.0f * 1.44269504088896f);
#pragma unroll
        for (int j = 0; j < 8; ++j) { qf[0][j] *= qs; qf[1][j] *= qs; }
    }

    f16x4 ones4;
#pragma unroll
    for (int j = 0; j < 4; ++j) ones4[j] = (f16_t)1.0f;

    f32x4 o[4], lacc;
#pragma unroll
    for (int r = 0; r < 4; ++r) o[r] = (f32x4){0.f, 0.f, 0.f, 0.f};
    lacc = (f32x4){0.f, 0.f, 0.f, 0.f};
    float m = -1e30f;   // running max for q = l15

    const int* mrow = mask + b * SS;
    const int* frow = flags + b * (SS / 128);

    const int srow8 = lane >> 3;
    const int gcolB = ((lane & 7) ^ srow8) * 8;
    const int NT = seq_len >> 7;

    // prologue: stage tile 0 into buffer 0
#pragma unroll
    for (int c = 0; c < 2; ++c) {
#pragma unroll
        for (int p = 0; p < 2; ++p) {
            const int i = wv * 2 + p;
            const int row = i * 8 + srow8;
            GLD_LDS(Kp + kb + (long)(c * 64 + row) * DKK + gcolB, &Ksh[0][c][i * 512]);
            GLD_LDS(Vtp + kb + (long)row * SS + c * 64 + gcolB, &Vsh[0][c][i * 512]);
        }
    }

#pragma unroll 1
    for (int tt = 0; tt < NT; ++tt) {
        const int cur = tt & 1;
        const int kt = tt << 7;
        __syncthreads();   // drains vmcnt/lgkm: buf[cur] staged, buf[cur^1] reads done

        if (tt + 1 < NT) {  // issue next-tile staging; hides under compute below
            const int kn = (tt + 1) << 7;
#pragma unroll
            for (int c = 0; c < 2; ++c) {
#pragma unroll
                for (int p = 0; p < 2; ++p) {
                    const int i = wv * 2 + p;
                    const int row = i * 8 + srow8;
                    GLD_LDS(Kp + kb + (long)(kn + c * 64 + row) * DKK + gcolB, &Ksh[cur ^ 1][c][i * 512]);
                    GLD_LDS(Vtp + kb + (long)row * SS + kn + c * 64 + gcolB, &Vsh[cur ^ 1][c][i * 512]);
                }
            }
        }

        // QK^T swapped: s[nt][r] = S[key = (nt>>2)*64 + (nt&3)*16 + quad*4 + r][q = l15]
        f32x4 s[8];
#pragma unroll
        for (int nt = 0; nt < 8; ++nt) s[nt] = (f32x4){0.f, 0.f, 0.f, 0.f};
#pragma unroll
        for (int nt = 0; nt < 8; ++nt) {
            const int c = nt >> 2;
            const int kr = (nt & 3) * 16 + l15;
#pragma unroll
            for (int dt = 0; dt < 2; ++dt) {
                f16x8 kf = *(const f16x8*)&Ksh[cur][c][kr * 64 + (((dt * 4 + quad) ^ (l15 & 7)) << 3)];
                s[nt] = __builtin_amdgcn_mfma_f32_16x16x32_f16(kf, qf[dt], s[nt], 0, 0, 0);
            }
        }

        if (!frow[kt >> 7]) {
#pragma unroll
            for (int nt = 0; nt < 8; ++nt) {
                i32x4 kp = *(const i32x4*)&mrow[kt + nt * 16 + quad * 4];
#pragma unroll
                for (int r = 0; r < 4; ++r)
                    s[nt][r] = kp[r] ? s[nt][r] : -1e30f;
            }
        }

        // max over this q-row's keys: in-lane (32 keys) then across the 4 quads
        f32x4 mx;
#pragma unroll
        for (int r = 0; r < 4; ++r)
            mx[r] = fmaxf(fmaxf(fmaxf(s[0][r], s[1][r]), fmaxf(s[2][r], s[3][r])),
                          fmaxf(fmaxf(s[4][r], s[5][r]), fmaxf(s[6][r], s[7][r])));
        float tm = fmaxf(fmaxf(mx[0], mx[1]), fmaxf(mx[2], mx[3]));
        tm = fmaxf(tm, __shfl_xor(tm, 16));
        tm = fmaxf(tm, __shfl_xor(tm, 32));

        const float mn = fmaxf(m, tm);
        if (__any(tm > m)) {  // wave-uniform; exact skip when all alpha == 1
            const float alpha = exp2f(m - mn);  // alpha for q = l15
            float a4[4];
#pragma unroll
            for (int r = 0; r < 4; ++r)
                a4[r] = __shfl(alpha, quad * 4 + r);  // alpha for q-row quad*4+r
#pragma unroll
            for (int t = 0; t < 4; ++t)
#pragma unroll
                for (int r = 0; r < 4; ++r) o[t][r] *= a4[r];
#pragma unroll
            for (int r = 0; r < 4; ++r) lacc[r] *= a4[r];
        }
        m = mn;

        // per 16-key group: exp -> pack (in-lane A-frag of 16x16x16) -> PV MFMA
#pragma unroll
        for (int nt = 0; nt < 8; ++nt) {
            const int c = nt >> 2;
            float p0 = exp2f(s[nt][0] - mn);
            float p1 = exp2f(s[nt][1] - mn);
            float p2 = exp2f(s[nt][2] - mn);
            float p3 = exp2f(s[nt][3] - mn);
            i32x2 pp;
            pp[0] = pkrtz(p0, p1);
            pp[1] = pkrtz(p2, p3);
            f16x4 paf = __builtin_bit_cast(f16x4, pp);
            // rowsum on MFMA pipe; lacc rows == o rows (q = quad*4+r)
            lacc = __builtin_amdgcn_mfma_f32_16x16x16f16(paf, ones4, lacc, 0, 0, 0);
            // V B-fragment: B[k = quad*4+j][col = l15 -> d], keys (nt&3)*16 + quad*4 + j
            const int vcol = ((((nt & 3) * 2 + (quad >> 1)) ^ (l15 & 7)) << 3) + ((quad & 1) << 2);
#pragma unroll
            for (int t = 0; t < 4; ++t) {
                f16x4 vB = *(const f16x4*)&Vsh[cur][c][(t * 16 + l15) * 64 + vcol];
                o[t] = __builtin_amdgcn_mfma_f32_16x16x16f16(paf, vB, o[t], 0, 0, 0);
            }
        }
        // no end barrier: next iteration's top barrier protects buffers
    }

    float inv[4];
#pragma unroll
    for (int r = 0; r < 4; ++r) inv[r] = 1.0f / lacc[r];
#pragma unroll
    for (int t = 0; t < 4; ++t) {
        int d = t * 16 + l15;
#pragma unroll
        for (int r = 0; r < 4; ++r) {
            int tok = b * SS + q0 + quad * 4 + r;
            ctx[(long)tok * DD + h * DKK + d] = (f16_t)(o[t][r] * inv[r]);
        }
    }
}

// ---------------------------------------------------------------- launch
extern "C" void kernel_launch(void* const* d_in, const int* in_sizes, int n_in,
                              void* d_out, int out_size, void* d_ws, size_t ws_size,
                              hipStream_t stream) {
    const float* x  = (const float*)d_in[0];
    const int* mask = (const int*)d_in[1];
    const float* Wq = (const float*)d_in[2];
    const float* bq = (const float*)d_in[3];
    const float* Wk = (const float*)d_in[4];
    const float* bk = (const float*)d_in[5];
    const float* Wv = (const float*)d_in[6];
    const float* bv = (const float*)d_in[7];
    const float* Wo = (const float*)d_in[8];
    const float* bo = (const float*)d_in[9];
    float* out = (float*)d_out;

    const long NX = (long)BB * SS * DD;  // 4194304
    const long NW = (long)DD * DD;       // 1048576

    char* ws = (char*)d_ws;
    f16_t* xf   = (f16_t*)ws; ws += NX * 2;
    f16_t* wqkh = (f16_t*)ws; ws += 2 * NW * 2;
    f16_t* wqkl = (f16_t*)ws; ws += 2 * NW * 2;
    f16_t* wvf  = (f16_t*)ws; ws += NW * 2;
    f16_t* wof  = (f16_t*)ws; ws += NW * 2;
    f16_t* qf   = (f16_t*)ws; ws += NX * 2;
    f16_t* kf   = (f16_t*)ws; ws += NX * 2;
    f16_t* vt   = (f16_t*)ws; ws += NX * 2;
    f16_t* ctx  = (f16_t*)ws; ws += NX * 2;
    int*   flg  = (int*)ws;   ws += 64 * 4;

    cast_x_flags<<<2048, 256, 0, stream>>>(x, xf, mask, flg, (int)NX);
    cast_wqk<<<2048, 256, 0, stream>>>(Wq, Wk, wqkh, wqkl, (int)NW);
    cast_wvo<<<2048, 256, 0, stream>>>(Wv, Wo, wvf, wof, (int)NW);

    dim3 gqkv(3 * DD / 128, (BB * SS) / 128);  // (24, 32) = 768 blocks
    gemm_qkv<<<gqkv, 256, 0, stream>>>(xf, wqkh, wqkl, wvf, bq, bk, bv, qf, kf, vt, DD);

    dim3 agrid(SS / 64, BH);  // (32, 32) = 1024 blocks
    attn_mfma8<<<agrid, 256, 0, stream>>>(qf, kf, vt, mask, flg, ctx, SS);

    dim3 go(DD / 128, (BB * SS) / 64);  // (8, 64) = 512 blocks
    gemm_o<<<go, 256, 0, stream>>>(ctx, wof, bo, out, DD, DD);
}

// Round 6
// 273.740 us; speedup vs baseline: 1.0526x; 1.0526x over previous
//
#include <hip/hip_runtime.h>
#include <hip/hip_bf16.h>
#include <math.h>

#define BB 2
#define SS 2048
#define DD 1024
#define HH 16
#define DKK 64
#define BH (BB * HH)          // 32

typedef __bf16 bf16_t;
typedef _Float16 f16_t;
typedef __attribute__((ext_vector_type(8))) _Float16 f16x8;
typedef __attribute__((ext_vector_type(4))) _Float16 f16x4;
typedef __attribute__((ext_vector_type(4))) float f32x4;
typedef __attribute__((ext_vector_type(4))) int i32x4;
typedef __attribute__((ext_vector_type(2))) int i32x2;

// async global->LDS, 16B per lane; lds base must be wave-uniform (lane*16 implicit)
#define GLD_LDS(gp, lp) __builtin_amdgcn_global_load_lds( \
    (const __attribute__((address_space(1))) void*)(gp),  \
    (__attribute__((address_space(3))) void*)(lp), 16, 0, 0)

static __device__ __forceinline__ int pkrtz(float a, float b) {
    auto h = __builtin_amdgcn_cvt_pkrtz(a, b);  // __fp16 ext_vector(2) on this clang
    return __builtin_bit_cast(int, h);
}

// ---------------------------------------------------------------- prep kernels
// x -> fp16, plus per-(b,128-key-block) all-keep flags
__global__ void cast_x_flags(const float* __restrict__ in, f16_t* __restrict__ out,
                             const int* __restrict__ mask, int* __restrict__ flags, int n) {
    int i = blockIdx.x * blockDim.x + threadIdx.x;
    int stride = gridDim.x * blockDim.x;
    for (; i < n; i += stride) out[i] = (f16_t)in[i];
    if (blockIdx.x == 0 && threadIdx.x < BB * (SS / 128)) {
        int f = threadIdx.x;
        int b = f / (SS / 128), t = f % (SS / 128);
        const int* p = mask + b * SS + t * 128;
        int all = 1;
        for (int j = 0; j < 128; ++j) all &= (p[j] != 0);
        flags[f] = all;
    }
}

// [Wq;Wk] -> fused fp16 hi + fp16 lo (lo = residual; may be subnormal)
__global__ void cast_wqk(const float* __restrict__ Wq, const float* __restrict__ Wk,
                         f16_t* __restrict__ hi, f16_t* __restrict__ lo, int nw) {
    int i = blockIdx.x * blockDim.x + threadIdx.x;
    int stride = gridDim.x * blockDim.x;
    for (; i < 2 * nw; i += stride) {
        float v = (i < nw) ? Wq[i] : Wk[i - nw];
        f16_t h = (f16_t)v;
        hi[i] = h;
        lo[i] = (f16_t)(v - (float)h);
    }
}

// Wv, Wo -> fp16
__global__ void cast_wvo(const float* __restrict__ Wv, const float* __restrict__ Wo,
                         f16_t* __restrict__ wv, f16_t* __restrict__ wo, int nw) {
    int i = blockIdx.x * blockDim.x + threadIdx.x;
    int stride = gridDim.x * blockDim.x;
    for (; i < 2 * nw; i += stride) {
        if (i < nw) wv[i] = (f16_t)Wv[i];
        else        wo[i - nw] = (f16_t)Wo[i - nw];
    }
}

// ---------------------------------------------------------------- fused QKV GEMM (fp16)
__global__ __launch_bounds__(256) void gemm_qkv(const f16_t* __restrict__ Af,
                                                const f16_t* __restrict__ Wqkh,
                                                const f16_t* __restrict__ Wqkl,
                                                const f16_t* __restrict__ Wvf,
                                                const float* __restrict__ bq,
                                                const float* __restrict__ bk,
                                                const float* __restrict__ bv,
                                                f16_t* __restrict__ q_o,
                                                f16_t* __restrict__ k_o,
                                                f16_t* __restrict__ vt_o,
                                                int K) {
    __shared__ __align__(16) f16_t sA[4096];
    __shared__ __align__(16) f16_t sB0[4096];
    __shared__ __align__(16) f16_t sB1[4096];

    const int tid  = threadIdx.x;
    const int wv   = tid >> 6;
    const int lane = tid & 63;
    const int quad = lane >> 4;
    const int l15  = lane & 15;
    const int wr   = wv >> 1;
    const int wc   = wv & 1;
    const int row0 = blockIdx.y * 128;
    const int col0 = blockIdx.x * 128;
    const bool isV = (col0 >= 2048);

    const f16_t* B0 = isV ? (Wvf + (long)(col0 - 2048) * K) : (Wqkh + (long)col0 * K);
    const f16_t* B1 = isV ? nullptr : (Wqkl + (long)col0 * K);

    f32x4 acc[4][4] = {};

    const int srow = tid >> 2;
    const int scol = (tid & 3) * 8;
    const long aoff = (long)(row0 + srow) * K + scol;
    const long boff = (long)srow * K + scol;

    if (isV) {
#pragma unroll 1
        for (int kb = 0; kb < K; kb += 32) {
#pragma unroll
            for (int p = 0; p < 2; ++p) {
                const long go = (long)p * 64 * K + kb;
                const int lo = p * 2048 + wv * 512;
                GLD_LDS(Af + aoff + go, sA + lo);
                GLD_LDS(B0 + boff + go, sB0 + lo);
            }
            __syncthreads();
            f16x8 af[4];
#pragma unroll
            for (int mt = 0; mt < 4; ++mt)
                af[mt] = *(const f16x8*)&sA[(wr * 64 + mt * 16 + l15) * 32 + quad * 8];
#pragma unroll
            for (int nt = 0; nt < 4; ++nt) {
                f16x8 b0 = *(const f16x8*)&sB0[(wc * 64 + nt * 16 + l15) * 32 + quad * 8];
#pragma unroll
                for (int mt = 0; mt < 4; ++mt)
                    acc[mt][nt] = __builtin_amdgcn_mfma_f32_16x16x32_f16(af[mt], b0, acc[mt][nt], 0, 0, 0);
            }
            __syncthreads();
        }
    } else {
#pragma unroll 1
        for (int kb = 0; kb < K; kb += 32) {
#pragma unroll
            for (int p = 0; p < 2; ++p) {
                const long go = (long)p * 64 * K + kb;
                const int lo = p * 2048 + wv * 512;
                GLD_LDS(Af + aoff + go, sA + lo);
                GLD_LDS(B0 + boff + go, sB0 + lo);
                GLD_LDS(B1 + boff + go, sB1 + lo);
            }
            __syncthreads();
            f16x8 af[4];
#pragma unroll
            for (int mt = 0; mt < 4; ++mt)
                af[mt] = *(const f16x8*)&sA[(wr * 64 + mt * 16 + l15) * 32 + quad * 8];
#pragma unroll
            for (int nt = 0; nt < 4; ++nt) {
                f16x8 b0 = *(const f16x8*)&sB0[(wc * 64 + nt * 16 + l15) * 32 + quad * 8];
                f16x8 b1 = *(const f16x8*)&sB1[(wc * 64 + nt * 16 + l15) * 32 + quad * 8];
#pragma unroll
                for (int mt = 0; mt < 4; ++mt) {
                    acc[mt][nt] = __builtin_amdgcn_mfma_f32_16x16x32_f16(af[mt], b0, acc[mt][nt], 0, 0, 0);
                    acc[mt][nt] = __builtin_amdgcn_mfma_f32_16x16x32_f16(af[mt], b1, acc[mt][nt], 0, 0, 0);
                }
            }
            __syncthreads();
        }
    }

    if (isV) {
#pragma unroll
        for (int nt = 0; nt < 4; ++nt) {
            const int colv = (col0 - 2048) + wc * 64 + nt * 16 + l15;  // [0,1024)
            const float bvv = bv[colv];
            const int hq = colv >> 6, dk = colv & 63;
#pragma unroll
            for (int mt = 0; mt < 4; ++mt) {
                const int grow0 = row0 + wr * 64 + mt * 16 + quad * 4;
                const int bq2 = grow0 >> 11;
                const int s0  = grow0 & (SS - 1);
                f16x4 pk;
#pragma unroll
                for (int r = 0; r < 4; ++r) pk[r] = (f16_t)(acc[mt][nt][r] + bvv);
                *(f16x4*)(vt_o + ((long)(bq2 * HH + hq) * DKK + dk) * SS + s0) = pk;
            }
        }
    } else {
        const bool isK = (col0 >= 1024);
        const float* bias = isK ? bk : bq;
        f16_t* op = isK ? k_o : q_o;
#pragma unroll
        for (int nt = 0; nt < 4; ++nt) {
            const int gcol = (col0 & 1023) + wc * 64 + nt * 16 + l15;
            const float bvv = bias[gcol];
            const int hq = gcol >> 6, dk = gcol & 63;
#pragma unroll
            for (int mt = 0; mt < 4; ++mt) {
                const int grow0 = row0 + wr * 64 + mt * 16 + quad * 4;
#pragma unroll
                for (int r = 0; r < 4; ++r) {
                    int grow = grow0 + r;
                    float vvv = acc[mt][nt][r] + bvv;
                    long off = (((long)(grow >> 11) * HH + hq) * SS + (grow & (SS - 1))) * DKK + dk;
                    op[off] = (f16_t)vvv;
                }
            }
        }
    }
}

// ---------------------------------------------------------------- O-projection GEMM (fp16 in, fp32 out)
__global__ __launch_bounds__(256) void gemm_o(const f16_t* __restrict__ Ah,
                                              const f16_t* __restrict__ Bhp,
                                              const float* __restrict__ bias,
                                              float* __restrict__ outf,
                                              int N, int K) {
    __shared__ __align__(16) f16_t lds[2048 + 4096];
    f16_t* Ash = lds;
    f16_t* Bsh = lds + 2048;

    const int tid  = threadIdx.x;
    const int wv   = tid >> 6;
    const int lane = tid & 63;
    const int quad = lane >> 4;
    const int l15  = lane & 15;
    const int wr   = wv >> 1;
    const int wc   = wv & 1;
    const int row0 = blockIdx.y * 64;
    const int col0 = blockIdx.x * 128;

    f32x4 acc[2][4] = {};

    const int srow = lane >> 2;
    const int scol = (lane & 3) * 8;
    const f16_t* gA  = Ah  + (long)(row0 + wv * 16 + srow) * K + scol;
    const f16_t* gB0 = Bhp + (long)(col0 + wv * 16 + srow) * K + scol;
    const f16_t* gB1 = Bhp + (long)(col0 + (wv + 4) * 16 + srow) * K + scol;
    f16_t* lA  = Ash + wv * 512;
    f16_t* lB0 = Bsh + wv * 512;
    f16_t* lB1 = Bsh + (wv + 4) * 512;

#pragma unroll 1
    for (int kb = 0; kb < K; kb += 32) {
        GLD_LDS(gA + kb, lA);
        GLD_LDS(gB0 + kb, lB0);
        GLD_LDS(gB1 + kb, lB1);
        __syncthreads();

        f16x8 af[2];
#pragma unroll
        for (int mt = 0; mt < 2; ++mt)
            af[mt] = *(const f16x8*)&Ash[(wr * 32 + mt * 16 + l15) * 32 + quad * 8];
#pragma unroll
        for (int nt = 0; nt < 4; ++nt) {
            f16x8 bh = *(const f16x8*)&Bsh[(wc * 64 + nt * 16 + l15) * 32 + quad * 8];
#pragma unroll
            for (int mt = 0; mt < 2; ++mt)
                acc[mt][nt] = __builtin_amdgcn_mfma_f32_16x16x32_f16(af[mt], bh, acc[mt][nt], 0, 0, 0);
        }
        __syncthreads();
    }

#pragma unroll
    for (int mt = 0; mt < 2; ++mt) {
#pragma unroll
        for (int nt = 0; nt < 4; ++nt) {
            const int gcol  = col0 + wc * 64 + nt * 16 + l15;
            const float bvv = bias[gcol];
            const int grow0 = row0 + wr * 32 + mt * 16 + quad * 4;
#pragma unroll
            for (int r = 0; r < 4; ++r)
                outf[(long)(grow0 + r) * N + gcol] = acc[mt][nt][r] + bvv;
        }
    }
}

// ---------------------------------------------------------------- MFMA flash attention v9
// 32 q-rows per wave (two 16-row groups, +0 and +64). K- and V-fragments are
// q-independent => each LDS read feeds BOTH groups' MFMAs: per-q LDS traffic
// and HBM staging halve, and the two groups give 2x independent ILP chains.
// Keeps v8's dbuf + one-barrier-per-tile + MFMA-pipe rowsum.
__global__ __launch_bounds__(256) void attn_mfma9(const f16_t* __restrict__ Qp,
                                                  const f16_t* __restrict__ Kp,
                                                  const f16_t* __restrict__ Vtp,
                                                  const int* __restrict__ mask,
                                                  const int* __restrict__ flags,
                                                  f16_t* __restrict__ ctx,
                                                  int seq_len) {
    __shared__ __align__(16) f16_t Ksh[2][2][4096];   // [buf][64-key sub-tile][...]
    __shared__ __align__(16) f16_t Vsh[2][2][4096];   // [buf][sub-tile] of V^T [d][key]

    const int tid  = threadIdx.x;
    const int wv   = tid >> 6;
    const int lane = tid & 63;
    const int quad = lane >> 4;
    const int l15  = lane & 15;
    const int bh   = blockIdx.y;
    const int b    = bh >> 4;
    const int h    = bh & 15;
    const int q0   = blockIdx.x * 128 + wv * 16;   // group 0 rows; group 1 = +64

    const long kb = (long)bh * SS * DKK;

    f16x8 qf0[2], qf1[2];
    {
        const f16_t* pq = Qp + kb + (long)(q0 + l15) * DKK + quad * 8;
        qf0[0] = *(const f16x8*)pq;
        qf0[1] = *(const f16x8*)(pq + 32);
        const f16_t* pq1 = pq + 64 * DKK;
        qf1[0] = *(const f16x8*)pq1;
        qf1[1] = *(const f16x8*)(pq1 + 32);
        const f16_t qs = (f16_t)(8.0f * 1.44269504088896f);
#pragma unroll
        for (int j = 0; j < 8; ++j) {
            qf0[0][j] *= qs; qf0[1][j] *= qs;
            qf1[0][j] *= qs; qf1[1][j] *= qs;
        }
    }

    f16x4 ones4;
#pragma unroll
    for (int j = 0; j < 4; ++j) ones4[j] = (f16_t)1.0f;

    f32x4 o0[4], o1[4], lacc0, lacc1;
#pragma unroll
    for (int r = 0; r < 4; ++r) {
        o0[r] = (f32x4){0.f, 0.f, 0.f, 0.f};
        o1[r] = (f32x4){0.f, 0.f, 0.f, 0.f};
    }
    lacc0 = (f32x4){0.f, 0.f, 0.f, 0.f};
    lacc1 = (f32x4){0.f, 0.f, 0.f, 0.f};
    float m0 = -1e30f, m1 = -1e30f;   // running max for q = l15 (per group)

    const int* mrow = mask + b * SS;
    const int* frow = flags + b * (SS / 128);

    const int srow8 = lane >> 3;
    const int gcolB = ((lane & 7) ^ srow8) * 8;
    const int NT = seq_len >> 7;

    // prologue: stage tile 0 into buffer 0
#pragma unroll
    for (int c = 0; c < 2; ++c) {
#pragma unroll
        for (int p = 0; p < 2; ++p) {
            const int i = wv * 2 + p;
            const int row = i * 8 + srow8;
            GLD_LDS(Kp + kb + (long)(c * 64 + row) * DKK + gcolB, &Ksh[0][c][i * 512]);
            GLD_LDS(Vtp + kb + (long)row * SS + c * 64 + gcolB, &Vsh[0][c][i * 512]);
        }
    }

#pragma unroll 1
    for (int tt = 0; tt < NT; ++tt) {
        const int cur = tt & 1;
        const int kt = tt << 7;
        __syncthreads();   // buf[cur] staged; buf[cur^1] reads from prev iter done

        if (tt + 1 < NT) {
            const int kn = (tt + 1) << 7;
#pragma unroll
            for (int c = 0; c < 2; ++c) {
#pragma unroll
                for (int p = 0; p < 2; ++p) {
                    const int i = wv * 2 + p;
                    const int row = i * 8 + srow8;
                    GLD_LDS(Kp + kb + (long)(kn + c * 64 + row) * DKK + gcolB, &Ksh[cur ^ 1][c][i * 512]);
                    GLD_LDS(Vtp + kb + (long)row * SS + kn + c * 64 + gcolB, &Vsh[cur ^ 1][c][i * 512]);
                }
            }
        }

        // QK^T swapped, shared K-fragments feed both q-groups
        f32x4 s0[8], s1[8];
#pragma unroll
        for (int nt = 0; nt < 8; ++nt) {
            s0[nt] = (f32x4){0.f, 0.f, 0.f, 0.f};
            s1[nt] = (f32x4){0.f, 0.f, 0.f, 0.f};
        }
#pragma unroll
        for (int nt = 0; nt < 8; ++nt) {
            const int c = nt >> 2;
            const int kr = (nt & 3) * 16 + l15;
#pragma unroll
            for (int dt = 0; dt < 2; ++dt) {
                f16x8 kf = *(const f16x8*)&Ksh[cur][c][kr * 64 + (((dt * 4 + quad) ^ (l15 & 7)) << 3)];
                s0[nt] = __builtin_amdgcn_mfma_f32_16x16x32_f16(kf, qf0[dt], s0[nt], 0, 0, 0);
                s1[nt] = __builtin_amdgcn_mfma_f32_16x16x32_f16(kf, qf1[dt], s1[nt], 0, 0, 0);
            }
        }

        if (!frow[kt >> 7]) {
#pragma unroll
            for (int nt = 0; nt < 8; ++nt) {
                i32x4 kp = *(const i32x4*)&mrow[kt + nt * 16 + quad * 4];
#pragma unroll
                for (int r = 0; r < 4; ++r) {
                    s0[nt][r] = kp[r] ? s0[nt][r] : -1e30f;
                    s1[nt][r] = kp[r] ? s1[nt][r] : -1e30f;
                }
            }
        }

        // per-group max over this q-row's keys (independent chains)
        f32x4 mxa, mxb;
#pragma unroll
        for (int r = 0; r < 4; ++r) {
            mxa[r] = fmaxf(fmaxf(fmaxf(s0[0][r], s0[1][r]), fmaxf(s0[2][r], s0[3][r])),
                           fmaxf(fmaxf(s0[4][r], s0[5][r]), fmaxf(s0[6][r], s0[7][r])));
            mxb[r] = fmaxf(fmaxf(fmaxf(s1[0][r], s1[1][r]), fmaxf(s1[2][r], s1[3][r])),
                           fmaxf(fmaxf(s1[4][r], s1[5][r]), fmaxf(s1[6][r], s1[7][r])));
        }
        float tm0 = fmaxf(fmaxf(mxa[0], mxa[1]), fmaxf(mxa[2], mxa[3]));
        float tm1 = fmaxf(fmaxf(mxb[0], mxb[1]), fmaxf(mxb[2], mxb[3]));
        tm0 = fmaxf(tm0, __shfl_xor(tm0, 16));
        tm1 = fmaxf(tm1, __shfl_xor(tm1, 16));
        tm0 = fmaxf(tm0, __shfl_xor(tm0, 32));
        tm1 = fmaxf(tm1, __shfl_xor(tm1, 32));

        const float mn0 = fmaxf(m0, tm0);
        const float mn1 = fmaxf(m1, tm1);
        if (__any(tm0 > m0)) {
            const float alpha = exp2f(m0 - mn0);
            float a4[4];
#pragma unroll
            for (int r = 0; r < 4; ++r) a4[r] = __shfl(alpha, quad * 4 + r);
#pragma unroll
            for (int t = 0; t < 4; ++t)
#pragma unroll
                for (int r = 0; r < 4; ++r) o0[t][r] *= a4[r];
#pragma unroll
            for (int r = 0; r < 4; ++r) lacc0[r] *= a4[r];
        }
        if (__any(tm1 > m1)) {
            const float alpha = exp2f(m1 - mn1);
            float a4[4];
#pragma unroll
            for (int r = 0; r < 4; ++r) a4[r] = __shfl(alpha, quad * 4 + r);
#pragma unroll
            for (int t = 0; t < 4; ++t)
#pragma unroll
                for (int r = 0; r < 4; ++r) o1[t][r] *= a4[r];
#pragma unroll
            for (int r = 0; r < 4; ++r) lacc1[r] *= a4[r];
        }
        m0 = mn0;
        m1 = mn1;

        // per 16-key group: exp -> pack -> PV MFMA; vB read once, used by both groups
#pragma unroll
        for (int nt = 0; nt < 8; ++nt) {
            const int c = nt >> 2;
            i32x2 pp0, pp1;
            pp0[0] = pkrtz(exp2f(s0[nt][0] - mn0), exp2f(s0[nt][1] - mn0));
            pp0[1] = pkrtz(exp2f(s0[nt][2] - mn0), exp2f(s0[nt][3] - mn0));
            pp1[0] = pkrtz(exp2f(s1[nt][0] - mn1), exp2f(s1[nt][1] - mn1));
            pp1[1] = pkrtz(exp2f(s1[nt][2] - mn1), exp2f(s1[nt][3] - mn1));
            f16x4 paf0 = __builtin_bit_cast(f16x4, pp0);
            f16x4 paf1 = __builtin_bit_cast(f16x4, pp1);
            lacc0 = __builtin_amdgcn_mfma_f32_16x16x16f16(paf0, ones4, lacc0, 0, 0, 0);
            lacc1 = __builtin_amdgcn_mfma_f32_16x16x16f16(paf1, ones4, lacc1, 0, 0, 0);
            const int vcol = ((((nt & 3) * 2 + (quad >> 1)) ^ (l15 & 7)) << 3) + ((quad & 1) << 2);
#pragma unroll
            for (int t = 0; t < 4; ++t) {
                f16x4 vB = *(const f16x4*)&Vsh[cur][c][(t * 16 + l15) * 64 + vcol];
                o0[t] = __builtin_amdgcn_mfma_f32_16x16x16f16(paf0, vB, o0[t], 0, 0, 0);
                o1[t] = __builtin_amdgcn_mfma_f32_16x16x16f16(paf1, vB, o1[t], 0, 0, 0);
            }
        }
    }

    float inv0[4], inv1[4];
#pragma unroll
    for (int r = 0; r < 4; ++r) {
        inv0[r] = 1.0f / lacc0[r];
        inv1[r] = 1.0f / lacc1[r];
    }
#pragma unroll
    for (int t = 0; t < 4; ++t) {
        int d = t * 16 + l15;
#pragma unroll
        for (int r = 0; r < 4; ++r) {
            int tok = b * SS + q0 + quad * 4 + r;
            ctx[(long)tok * DD + h * DKK + d] = (f16_t)(o0[t][r] * inv0[r]);
            ctx[(long)(tok + 64) * DD + h * DKK + d] = (f16_t)(o1[t][r] * inv1[r]);
        }
    }
}

// ---------------------------------------------------------------- launch
extern "C" void kernel_launch(void* const* d_in, const int* in_sizes, int n_in,
                              void* d_out, int out_size, void* d_ws, size_t ws_size,
                              hipStream_t stream) {
    const float* x  = (const float*)d_in[0];
    const int* mask = (const int*)d_in[1];
    const float* Wq = (const float*)d_in[2];
    const float* bq = (const float*)d_in[3];
    const float* Wk = (const float*)d_in[4];
    const float* bk = (const float*)d_in[5];
    const float* Wv = (const float*)d_in[6];
    const float* bv = (const float*)d_in[7];
    const float* Wo = (const float*)d_in[8];
    const float* bo = (const float*)d_in[9];
    float* out = (float*)d_out;

    const long NX = (long)BB * SS * DD;  // 4194304
    const long NW = (long)DD * DD;       // 1048576

    char* ws = (char*)d_ws;
    f16_t* xf   = (f16_t*)ws; ws += NX * 2;
    f16_t* wqkh = (f16_t*)ws; ws += 2 * NW * 2;
    f16_t* wqkl = (f16_t*)ws; ws += 2 * NW * 2;
    f16_t* wvf  = (f16_t*)ws; ws += NW * 2;
    f16_t* wof  = (f16_t*)ws; ws += NW * 2;
    f16_t* qf   = (f16_t*)ws; ws += NX * 2;
    f16_t* kf   = (f16_t*)ws; ws += NX * 2;
    f16_t* vt   = (f16_t*)ws; ws += NX * 2;
    f16_t* ctx  = (f16_t*)ws; ws += NX * 2;
    int*   flg  = (int*)ws;   ws += 64 * 4;

    cast_x_flags<<<2048, 256, 0, stream>>>(x, xf, mask, flg, (int)NX);
    cast_wqk<<<2048, 256, 0, stream>>>(Wq, Wk, wqkh, wqkl, (int)NW);
    cast_wvo<<<2048, 256, 0, stream>>>(Wv, Wo, wvf, wof, (int)NW);

    dim3 gqkv(3 * DD / 128, (BB * SS) / 128);  // (24, 32) = 768 blocks
    gemm_qkv<<<gqkv, 256, 0, stream>>>(xf, wqkh, wqkl, wvf, bq, bk, bv, qf, kf, vt, DD);

    dim3 agrid(SS / 128, BH);  // (16, 32) = 512 blocks, 128 q-rows each
    attn_mfma9<<<agrid, 256, 0, stream>>>(qf, kf, vt, mask, flg, ctx, SS);

    dim3 go(DD / 128, (BB * SS) / 64);  // (8, 64) = 512 blocks
    gemm_o<<<go, 256, 0, stream>>>(ctx, wof, bo, out, DD, DD);
}